// Round 7
// baseline (318.531 us; speedup 1.0000x reference)
//
#include <hip/hip_runtime.h>
#include <hip/hip_bf16.h>

// Problem constants
#define BGR   256                 // graphs
#define NPG1  512                 // nodes per graph (input)
#define DEG   16
#define EPG   (NPG1 * DEG)        // 8192 edges per graph
#define LB    5                   // lookback features
#define DIM   64
#define OUTF  6
#define NN    (BGR * NPG1)        // 131,072
#define EDG   (BGR * EPG)         // 2,097,152
#define K1    410                 // ceil(0.8*512)
#define K2    328                 // ceil(0.8*410)
#define N1    (BGR * K1)          // 104,960
#define CSRW  64                  // CSR slots per node (max in-degree ~40)
#define SPLIT 4                   // aggregation sub-blocks per graph
#define EPS   (EPG / SPLIT)       // 2048 edges per sub-block
#define GRID2 (N1 / 64)           // 1640 conv2 blocks (64 nodes each)

// ---------------------------------------------------------------------------
// s1_agg: per (graph, quarter) block aggregates 2048 edges into LDS, writes
// PARTIAL sums + degrees to global (no global atomics). Grid = 1024, LDS 22KB.
__global__ __launch_bounds__(512)
void s1_agg_kernel(const float* __restrict__ x,
                   const int* __restrict__ eidx,
                   float* __restrict__ part_s,
                   int* __restrict__ part_d) {
    __shared__ __align__(16) float xl[NPG1 * LB];
    __shared__ __align__(16) float sums[NPG1 * LB];
    __shared__ int degi[NPG1];

    const int bid = blockIdx.x;               // g*SPLIT + p
    const int g = bid >> 2;
    const int p = bid & 3;
    const int t = threadIdx.x;
    const int* __restrict__ src = eidx;
    const int* __restrict__ dst = eidx + EDG;

    {
        const float4* x4 = (const float4*)(x + (size_t)g * (NPG1 * LB));
        float4* xl4 = (float4*)xl;
        float4* sm4 = (float4*)sums;
        const float4 z4 = make_float4(0.f, 0.f, 0.f, 0.f);
        #pragma unroll
        for (int k = 0; k < 2; ++k) {
            int i = k * 512 + t;
            if (i < NPG1 * LB / 4) { xl4[i] = x4[i]; sm4[i] = z4; }
        }
        degi[t] = 0;
    }
    __syncthreads();

    const int ebase = g * EPG + p * EPS;
    #pragma unroll
    for (int k = 0; k < EPS / 512; ++k) {     // 4 edges per thread
        int e = ebase + k * 512 + t;
        int s = src[e] & (NPG1 - 1);
        int d = dst[e] & (NPG1 - 1);
        #pragma unroll
        for (int j = 0; j < LB; ++j)
            unsafeAtomicAdd(&sums[d * LB + j], xl[s * LB + j]);
        atomicAdd(&degi[d], 1);
    }
    __syncthreads();

    {   // coalesced partial write-out
        float4* ps4 = (float4*)(part_s + (size_t)bid * (NPG1 * LB));
        const float4* ls4 = (const float4*)sums;
        #pragma unroll
        for (int k = 0; k < 2; ++k) {
            int i = k * 512 + t;
            if (i < NPG1 * LB / 4) ps4[i] = ls4[i];
        }
        part_d[bid * NPG1 + t] = degi[t];
    }
}

// ---------------------------------------------------------------------------
// s1_score: node-parallel, full occupancy. Combine partials -> mean, compute
// conv1 row + pooling score per node (uniform weight loads). Writes mean+score.
__global__ __launch_bounds__(256)
void s1_score_kernel(const float* __restrict__ x,
                     const float* __restrict__ part_s,
                     const int* __restrict__ part_d,
                     const float* __restrict__ Wl,
                     const float* __restrict__ bl,
                     const float* __restrict__ Wr,
                     const float* __restrict__ pw,
                     float* __restrict__ meanv,
                     float* __restrict__ sc1g) {
    const int n = blockIdx.x * 256 + threadIdx.x;    // grid = NN/256 exact
    const int g = n >> 9, lo = n & (NPG1 - 1);

    float s0 = 0.f, s1 = 0.f, s2 = 0.f, s3 = 0.f, s4 = 0.f;
    int dg = 0;
    #pragma unroll
    for (int p = 0; p < SPLIT; ++p) {
        const float* ps = part_s + (size_t)(g * SPLIT + p) * (NPG1 * LB) + lo * LB;
        s0 += ps[0]; s1 += ps[1]; s2 += ps[2]; s3 += ps[3]; s4 += ps[4];
        dg += part_d[(g * SPLIT + p) * NPG1 + lo];
    }
    const float invd = 1.f / fmaxf((float)dg, 1.f);
    float m[LB]  = { s0 * invd, s1 * invd, s2 * invd, s3 * invd, s4 * invd };
    float xv[LB];
    const float* xr = x + (size_t)n * LB;
    #pragma unroll
    for (int j = 0; j < LB; ++j) { xv[j] = xr[j]; meanv[(size_t)n * LB + j] = m[j]; }

    const float4* Wl4 = (const float4*)Wl;
    const float4* Wr4 = (const float4*)Wr;
    const float4* bl4 = (const float4*)bl;
    const float4* pw4 = (const float4*)pw;
    float p = 0.f, q = 0.f;
    #pragma unroll 4
    for (int d4 = 0; d4 < DIM / 4; ++d4) {
        float4 bb = bl4[d4];
        float4 ww = pw4[d4];
        float4 h = bb;
        #pragma unroll
        for (int j = 0; j < LB; ++j) {
            float4 a = Wl4[j * (DIM / 4) + d4];
            float4 b = Wr4[j * (DIM / 4) + d4];
            h.x += m[j] * a.x + xv[j] * b.x;
            h.y += m[j] * a.y + xv[j] * b.y;
            h.z += m[j] * a.z + xv[j] * b.z;
            h.w += m[j] * a.w + xv[j] * b.w;
        }
        h.x = fmaxf(h.x, 0.f); h.y = fmaxf(h.y, 0.f);
        h.z = fmaxf(h.z, 0.f); h.w = fmaxf(h.w, 0.f);
        p += h.x * ww.x + h.y * ww.y + h.z * ww.z + h.w * ww.w;
        q += ww.x * ww.x + ww.y * ww.y + ww.z * ww.z + ww.w * ww.w;
    }
    sc1g[n] = tanhf(p / sqrtf(q));
}

// ---------------------------------------------------------------------------
// s1_rankpool: per-graph. Rank scores, write inv map, recompute kept rows
// (from mean+x), write scaled h1p + readout x1.
__global__ __launch_bounds__(512)
void s1_rankpool_kernel(const float* __restrict__ x,
                        const float* __restrict__ meanv,
                        const float* __restrict__ sc1g,
                        const float* __restrict__ Wl,
                        const float* __restrict__ bl,
                        const float* __restrict__ Wr,
                        float* __restrict__ h1p,
                        int* __restrict__ invr,
                        float* __restrict__ x1buf) {
    __shared__ __align__(16) float sc[NPG1];
    __shared__ int   rnk[NPG1];
    __shared__ float redmx[8 * DIM];
    __shared__ float redsm[8 * DIM];

    const int g = blockIdx.x, t = threadIdx.x;
    const int wid = t >> 6, lane = t & 63;

    sc[t] = sc1g[g * NPG1 + t];
    __syncthreads();

    {
        float my = sc[t];
        int r = 0;
        const float4* sc4 = (const float4*)sc;
        #pragma unroll 4
        for (int j4 = 0; j4 < NPG1 / 4; ++j4) {
            float4 v = sc4[j4];
            int j = 4 * j4;
            r += (v.x > my) | ((v.x == my) & (j     < t));
            r += (v.y > my) | ((v.y == my) & (j + 1 < t));
            r += (v.z > my) | ((v.z == my) & (j + 2 < t));
            r += (v.w > my) | ((v.w == my) & (j + 3 < t));
        }
        rnk[t] = r;
        invr[g * NPG1 + t] = (r < K1) ? r : -1;
    }
    __syncthreads();

    float wlv[LB], wrv[LB];
    #pragma unroll
    for (int j = 0; j < LB; ++j) { wlv[j] = Wl[j * DIM + lane]; wrv[j] = Wr[j * DIM + lane]; }
    const float blv = bl[lane];

    float mx = -INFINITY, sm = 0.f;
    for (int n = wid; n < NPG1; n += 8) {
        int r = rnk[n];
        if (r >= K1) continue;
        const float* mp = meanv + (size_t)(g * NPG1 + n) * LB;
        const float* xp = x + (size_t)(g * NPG1 + n) * LB;
        float al = 0.f, ar = 0.f;
        #pragma unroll
        for (int j = 0; j < LB; ++j) {
            al += mp[j] * wlv[j];
            ar += xp[j] * wrv[j];
        }
        float acc = fmaxf(blv + al + ar, 0.f);
        float v = acc * sc[n];
        h1p[((size_t)g * K1 + r) * DIM + lane] = v;
        mx = fmaxf(mx, v);
        sm += v;
    }
    redmx[wid * DIM + lane] = mx;
    redsm[wid * DIM + lane] = sm;
    __syncthreads();
    if (wid == 0) {
        float m2 = redmx[lane], s2 = redsm[lane];
        #pragma unroll
        for (int w = 1; w < 8; ++w) {
            m2 = fmaxf(m2, redmx[w * DIM + lane]);
            s2 += redsm[w * DIM + lane];
        }
        x1buf[g * 2 * DIM + lane]       = m2;
        x1buf[g * 2 * DIM + DIM + lane] = s2 * (1.0f / (float)K1);
    }
}

// ---------------------------------------------------------------------------
// CSR fill: edge-parallel, full occupancy.
__global__ __launch_bounds__(256)
void csr_fill_kernel(const int* __restrict__ eidx,
                     const int* __restrict__ invr,
                     int* __restrict__ csr,
                     int* __restrict__ indeg) {
    int e = blockIdx.x * 256 + threadIdx.x;       // grid = EDG/256 exact
    int s = eidx[e];
    int d = eidx[EDG + e];
    int rs = invr[s];
    int rd = invr[d];
    if ((rs | rd) < 0) return;                    // either dropped
    int g = s >> 9;
    int gn = g * K1 + rd;
    int slot = atomicAdd(&indeg[gn], 1);
    csr[(size_t)gn * CSRW + slot] = g * K1 + rs;
}

// ---------------------------------------------------------------------------
// conv2: 8 nodes per wave, 8 waves (64 nodes) per block, XCD-swizzled grid.
__global__ __launch_bounds__(512)
void conv2_kernel(const float* __restrict__ h1p,
                  const int* __restrict__ csr,
                  const int* __restrict__ indeg,
                  const float* __restrict__ Wl,
                  const float* __restrict__ bl,
                  const float* __restrict__ Wr,
                  const float* __restrict__ pw,
                  float* __restrict__ h2,
                  float* __restrict__ sc2g) {
    __shared__ __align__(16) float wls[DIM * DIM];      // 16 KB
    __shared__ __align__(16) float wrs[DIM * DIM];      // 16 KB
    __shared__ __align__(16) float mst[8][8][DIM];      // 16 KB

    const int t = threadIdx.x, wid = t >> 6, lane = t & 63;
    for (int i = t; i < DIM * DIM; i += 512) { wls[i] = Wl[i]; wrs[i] = Wr[i]; }

    const float blv = bl[lane], pwv = pw[lane];
    float qq = pwv * pwv;
    #pragma unroll
    for (int o = 32; o; o >>= 1) qq += __shfl_xor(qq, o);
    const float inv_nrm = 1.f / sqrtf(qq);

    // XCD swizzle: consecutive compute-ids share an XCD (GRID2 % 8 == 0)
    const int cid = (blockIdx.x & 7) * (GRID2 / 8) + (blockIdx.x >> 3);
    const int nb = cid * 64 + wid * 8;            // this wave's 8 nodes

    int dg[8];
    #pragma unroll
    for (int i = 0; i < 8; ++i) dg[i] = indeg[nb + i];
    int dgmax = 0;
    #pragma unroll
    for (int i = 0; i < 8; ++i) dgmax = max(dgmax, dg[i]);

    float a[8] = {0.f, 0.f, 0.f, 0.f, 0.f, 0.f, 0.f, 0.f};
    for (int kc = 0; 4 * kc < dgmax; ++kc) {
        const int k0 = 4 * kc;
        #pragma unroll
        for (int i = 0; i < 8; ++i) {
            int4 id4 = *(const int4*)&csr[(size_t)(nb + i) * CSRW + k0];
            #define GACC(idv, kk)                                          \
            {   int   _id = ((kk) < dg[i]) ? (idv) : (nb + i);             \
                float _v  = h1p[(size_t)_id * DIM + lane];                 \
                a[i] += ((kk) < dg[i]) ? _v : 0.f; }
            GACC(id4.x, k0) GACC(id4.y, k0 + 1) GACC(id4.z, k0 + 2) GACC(id4.w, k0 + 3)
            #undef GACC
        }
    }
    #pragma unroll
    for (int i = 0; i < 8; ++i)
        mst[wid][i][lane] = a[i] * (1.f / fmaxf((float)dg[i], 1.f));
    __syncthreads();                              // covers wls/wrs staging

    float lacc[8] = {0.f, 0.f, 0.f, 0.f, 0.f, 0.f, 0.f, 0.f};
    float racc[8] = {0.f, 0.f, 0.f, 0.f, 0.f, 0.f, 0.f, 0.f};
    #pragma unroll 2
    for (int j4 = 0; j4 < DIM / 4; ++j4) {
        const int jb = 4 * j4 * DIM + lane;
        float w0 = wls[jb],           w1 = wls[jb + DIM];
        float w2 = wls[jb + 2 * DIM], w3 = wls[jb + 3 * DIM];
        float u0 = wrs[jb],           u1 = wrs[jb + DIM];
        float u2 = wrs[jb + 2 * DIM], u3 = wrs[jb + 3 * DIM];
        #pragma unroll
        for (int i = 0; i < 8; ++i) {
            float4 m  = ((const float4*)&mst[wid][i][0])[j4];
            float4 xq = ((const float4*)&h1p[(size_t)(nb + i) * DIM])[j4];
            lacc[i] += m.x  * w0 + m.y  * w1 + m.z  * w2 + m.w  * w3;
            racc[i] += xq.x * u0 + xq.y * u1 + xq.z * u2 + xq.w * u3;
        }
    }
    float pv[8];
    #pragma unroll
    for (int i = 0; i < 8; ++i) {
        float h = fmaxf(blv + lacc[i] + racc[i], 0.f);
        h2[(size_t)(nb + i) * DIM + lane] = h;
        pv[i] = h * pwv;
    }
    #pragma unroll
    for (int o = 32; o; o >>= 1) {
        #pragma unroll
        for (int i = 0; i < 8; ++i) pv[i] += __shfl_xor(pv[i], o);
    }
    if (lane == 0) {
        #pragma unroll
        for (int i = 0; i < 8; ++i) sc2g[nb + i] = tanhf(pv[i] * inv_nrm);
    }
}

// ---------------------------------------------------------------------------
// Pool2 + readout2 + final MLP (one block per graph).
__global__ __launch_bounds__(512)
void pool2_mlp_kernel(const float* __restrict__ sc2g,
                      const float* __restrict__ h2,
                      const float* __restrict__ x1buf,
                      const float* __restrict__ W1,
                      const float* __restrict__ b1,
                      const float* __restrict__ W2,
                      const float* __restrict__ b2,
                      float* __restrict__ out) {
    __shared__ __align__(16) float sc2[412];
    __shared__ int   rnk2[K1];
    __shared__ float redmx[8 * DIM];
    __shared__ float redsm[8 * DIM];
    __shared__ float zy[2 * DIM + DIM];

    const int g = blockIdx.x, t = threadIdx.x;
    const int wid = t >> 6, lane = t & 63;

    if (t < K1) sc2[t] = sc2g[g * K1 + t];
    if (t >= K1 && t < 412) sc2[t] = -INFINITY;
    __syncthreads();

    if (t < K1) {
        float my = sc2[t];
        int r = 0;
        const float4* sc4 = (const float4*)sc2;
        #pragma unroll 4
        for (int j4 = 0; j4 < 103; ++j4) {
            float4 v = sc4[j4];
            int j = 4 * j4;
            r += (v.x > my) | ((v.x == my) & (j     < t));
            r += (v.y > my) | ((v.y == my) & (j + 1 < t));
            r += (v.z > my) | ((v.z == my) & (j + 2 < t));
            r += (v.w > my) | ((v.w == my) & (j + 3 < t));
        }
        rnk2[t] = r;
    }
    __syncthreads();

    float mx = -INFINITY, sm = 0.f;
    for (int n = wid; n < K1; n += 8) {
        if (rnk2[n] < K2) {
            float v = h2[((size_t)g * K1 + n) * DIM + lane] * sc2[n];
            mx = fmaxf(mx, v);
            sm += v;
        }
    }
    redmx[wid * DIM + lane] = mx;
    redsm[wid * DIM + lane] = sm;
    __syncthreads();
    if (wid == 0) {
        float m2 = redmx[lane], s2 = redsm[lane];
        #pragma unroll
        for (int w = 1; w < 8; ++w) {
            m2 = fmaxf(m2, redmx[w * DIM + lane]);
            s2 += redsm[w * DIM + lane];
        }
        zy[lane]       = x1buf[g * 2 * DIM + lane]       + m2;
        zy[DIM + lane] = x1buf[g * 2 * DIM + DIM + lane] + s2 * (1.0f / (float)K2);
    }
    __syncthreads();

    if (t < DIM) {
        float a = b1[t];
        #pragma unroll 8
        for (int j = 0; j < 2 * DIM; ++j) a += zy[j] * W1[j * DIM + t];
        zy[2 * DIM + t] = fmaxf(a, 0.f);
    }
    __syncthreads();
    if (t < OUTF) {
        float a = b2[t];
        #pragma unroll
        for (int j = 0; j < DIM; ++j) a += zy[2 * DIM + j] * W2[j * OUTF + t];
        out[g * OUTF + t] = a;
    }
}

// ---------------------------------------------------------------------------
extern "C" void kernel_launch(void* const* d_in, const int* in_sizes, int n_in,
                              void* d_out, int out_size, void* d_ws, size_t ws_size,
                              hipStream_t stream) {
    (void)in_sizes; (void)n_in; (void)out_size; (void)ws_size;
    const float* x       = (const float*)d_in[0];
    const int*   eidx    = (const int*)d_in[1];
    const float* c1_Wl   = (const float*)d_in[2];
    const float* c1_bl   = (const float*)d_in[3];
    const float* c1_Wr   = (const float*)d_in[4];
    const float* pool1_w = (const float*)d_in[5];
    const float* c2_Wl   = (const float*)d_in[6];
    const float* c2_bl   = (const float*)d_in[7];
    const float* c2_Wr   = (const float*)d_in[8];
    const float* pool2_w = (const float*)d_in[9];
    const float* lin1_W  = (const float*)d_in[10];
    const float* lin1_b  = (const float*)d_in[11];
    const float* lin2_W  = (const float*)d_in[12];
    const float* lin2_b  = (const float*)d_in[13];
    float* out = (float*)d_out;

    // Workspace layout (256-aligned), ~83 MB with overlays
    char* w = (char*)d_ws;
    size_t off = 0;
    auto alloc = [&](size_t bytes) {
        void* p = w + off;
        off = (off + bytes + 255) & ~(size_t)255;
        return p;
    };
    float* h1p   = (float*)alloc((size_t)N1 * DIM * 4);        // 26.9 MB
    int*   invr  = (int*)  alloc((size_t)NN * 4);              // 512 KB
    float* x1buf = (float*)alloc((size_t)BGR * 2 * DIM * 4);   // 128 KB
    float* sc2g  = (float*)alloc((size_t)N1 * 4);              // 410 KB
    int*   indeg = (int*)  alloc((size_t)N1 * 4);              // 410 KB
    char*  h2reg = (char*) alloc((size_t)N1 * DIM * 4);        // 26.9 MB
    char*  csreg = (char*) alloc((size_t)N1 * CSRW * 4);       // 26.9 MB

    // Overlays: partials live in h2 region (consumed before conv2 writes h2);
    // mean+sc1 live in csr region (consumed before csr_fill writes csr).
    float* h2     = (float*)h2reg;
    float* part_s = (float*)h2reg;                             // 10.5 MB
    int*   part_d = (int*)(part_s + (size_t)BGR * SPLIT * NPG1 * LB); // 2.1 MB
    int*   csr    = (int*)csreg;
    float* meanv  = (float*)csreg;                             // 2.6 MB
    float* sc1g   = meanv + (size_t)NN * LB;                   // 512 KB

    hipMemsetAsync(indeg, 0, (size_t)N1 * 4, stream);

    s1_agg_kernel<<<BGR * SPLIT, 512, 0, stream>>>(x, eidx, part_s, part_d);
    s1_score_kernel<<<NN / 256, 256, 0, stream>>>(x, part_s, part_d, c1_Wl,
                                                  c1_bl, c1_Wr, pool1_w,
                                                  meanv, sc1g);
    s1_rankpool_kernel<<<BGR, 512, 0, stream>>>(x, meanv, sc1g, c1_Wl, c1_bl,
                                                c1_Wr, h1p, invr, x1buf);
    csr_fill_kernel<<<EDG / 256, 256, 0, stream>>>(eidx, invr, csr, indeg);
    conv2_kernel<<<GRID2, 512, 0, stream>>>(h1p, csr, indeg, c2_Wl, c2_bl,
                                            c2_Wr, pool2_w, h2, sc2g);
    pool2_mlp_kernel<<<BGR, 512, 0, stream>>>(sc2g, h2, x1buf, lin1_W, lin1_b,
                                              lin2_W, lin2_b, out);
}

// Round 8
// 313.468 us; speedup vs baseline: 1.0162x; 1.0162x over previous
//
#include <hip/hip_runtime.h>
#include <hip/hip_bf16.h>

// Problem constants
#define BGR   256                 // graphs
#define NPG1  512                 // nodes per graph (input)
#define DEG   16
#define EPG   (NPG1 * DEG)        // 8192 edges per graph
#define LB    5                   // lookback features
#define DIM   64
#define OUTF  6
#define NN    (BGR * NPG1)        // 131,072
#define EDG   (BGR * EPG)         // 2,097,152
#define K1    410                 // ceil(0.8*512)
#define K2    328                 // ceil(0.8*410)
#define N1    (BGR * K1)          // 104,960
#define ZROW  N1                  // zero-row index in Y_l
#define CSRW  48                  // CSR slots per node (max pooled in-deg ~35)
#define SPLIT 4                   // s1 aggregation sub-blocks per graph
#define EPS   (EPG / SPLIT)       // 2048 edges per sub-block
#define GRIDG (N1 / 64)           // 1640 gemm12 blocks
#define GRIDA (N1 / 16)           // 6560 gather2 blocks

// ---------------------------------------------------------------------------
// s1_agg: per (graph, quarter) block aggregates 2048 edges into LDS, writes
// PARTIAL sums + degrees to global (no global atomics).
__global__ __launch_bounds__(512)
void s1_agg_kernel(const float* __restrict__ x,
                   const int* __restrict__ eidx,
                   float* __restrict__ part_s,
                   int* __restrict__ part_d) {
    __shared__ __align__(16) float xl[NPG1 * LB];
    __shared__ __align__(16) float sums[NPG1 * LB];
    __shared__ int degi[NPG1];

    const int bid = blockIdx.x;               // g*SPLIT + p
    const int g = bid >> 2;
    const int p = bid & 3;
    const int t = threadIdx.x;
    const int* __restrict__ src = eidx;
    const int* __restrict__ dst = eidx + EDG;

    {
        const float4* x4 = (const float4*)(x + (size_t)g * (NPG1 * LB));
        float4* xl4 = (float4*)xl;
        float4* sm4 = (float4*)sums;
        const float4 z4 = make_float4(0.f, 0.f, 0.f, 0.f);
        #pragma unroll
        for (int k = 0; k < 2; ++k) {
            int i = k * 512 + t;
            if (i < NPG1 * LB / 4) { xl4[i] = x4[i]; sm4[i] = z4; }
        }
        degi[t] = 0;
    }
    __syncthreads();

    const int ebase = g * EPG + p * EPS;
    #pragma unroll
    for (int k = 0; k < EPS / 512; ++k) {     // 4 edges per thread
        int e = ebase + k * 512 + t;
        int s = src[e] & (NPG1 - 1);
        int d = dst[e] & (NPG1 - 1);
        #pragma unroll
        for (int j = 0; j < LB; ++j)
            unsafeAtomicAdd(&sums[d * LB + j], xl[s * LB + j]);
        atomicAdd(&degi[d], 1);
    }
    __syncthreads();

    {
        float4* ps4 = (float4*)(part_s + (size_t)bid * (NPG1 * LB));
        const float4* ls4 = (const float4*)sums;
        #pragma unroll
        for (int k = 0; k < 2; ++k) {
            int i = k * 512 + t;
            if (i < NPG1 * LB / 4) ps4[i] = ls4[i];
        }
        part_d[bid * NPG1 + t] = degi[t];
    }
}

// ---------------------------------------------------------------------------
// s1_score: node-parallel, full occupancy.
__global__ __launch_bounds__(256)
void s1_score_kernel(const float* __restrict__ x,
                     const float* __restrict__ part_s,
                     const int* __restrict__ part_d,
                     const float* __restrict__ Wl,
                     const float* __restrict__ bl,
                     const float* __restrict__ Wr,
                     const float* __restrict__ pw,
                     float* __restrict__ meanv,
                     float* __restrict__ sc1g) {
    const int n = blockIdx.x * 256 + threadIdx.x;    // grid = NN/256 exact
    const int g = n >> 9, lo = n & (NPG1 - 1);

    float s0 = 0.f, s1 = 0.f, s2 = 0.f, s3 = 0.f, s4 = 0.f;
    int dg = 0;
    #pragma unroll
    for (int p = 0; p < SPLIT; ++p) {
        const float* ps = part_s + (size_t)(g * SPLIT + p) * (NPG1 * LB) + lo * LB;
        s0 += ps[0]; s1 += ps[1]; s2 += ps[2]; s3 += ps[3]; s4 += ps[4];
        dg += part_d[(g * SPLIT + p) * NPG1 + lo];
    }
    const float invd = 1.f / fmaxf((float)dg, 1.f);
    float m[LB]  = { s0 * invd, s1 * invd, s2 * invd, s3 * invd, s4 * invd };
    float xv[LB];
    const float* xr = x + (size_t)n * LB;
    #pragma unroll
    for (int j = 0; j < LB; ++j) { xv[j] = xr[j]; meanv[(size_t)n * LB + j] = m[j]; }

    const float4* Wl4 = (const float4*)Wl;
    const float4* Wr4 = (const float4*)Wr;
    const float4* bl4 = (const float4*)bl;
    const float4* pw4 = (const float4*)pw;
    float p = 0.f, q = 0.f;
    #pragma unroll 4
    for (int d4 = 0; d4 < DIM / 4; ++d4) {
        float4 bb = bl4[d4];
        float4 ww = pw4[d4];
        float4 h = bb;
        #pragma unroll
        for (int j = 0; j < LB; ++j) {
            float4 a = Wl4[j * (DIM / 4) + d4];
            float4 b = Wr4[j * (DIM / 4) + d4];
            h.x += m[j] * a.x + xv[j] * b.x;
            h.y += m[j] * a.y + xv[j] * b.y;
            h.z += m[j] * a.z + xv[j] * b.z;
            h.w += m[j] * a.w + xv[j] * b.w;
        }
        h.x = fmaxf(h.x, 0.f); h.y = fmaxf(h.y, 0.f);
        h.z = fmaxf(h.z, 0.f); h.w = fmaxf(h.w, 0.f);
        p += h.x * ww.x + h.y * ww.y + h.z * ww.z + h.w * ww.w;
        q += ww.x * ww.x + ww.y * ww.y + ww.z * ww.z + ww.w * ww.w;
    }
    sc1g[n] = tanhf(p / sqrtf(q));
}

// ---------------------------------------------------------------------------
// s1_rankpool: per-graph rank + kept-row recompute + h1p + readout x1.
__global__ __launch_bounds__(512)
void s1_rankpool_kernel(const float* __restrict__ x,
                        const float* __restrict__ meanv,
                        const float* __restrict__ sc1g,
                        const float* __restrict__ Wl,
                        const float* __restrict__ bl,
                        const float* __restrict__ Wr,
                        float* __restrict__ h1p,
                        int* __restrict__ invr,
                        float* __restrict__ x1buf) {
    __shared__ __align__(16) float sc[NPG1];
    __shared__ int   rnk[NPG1];
    __shared__ float redmx[8 * DIM];
    __shared__ float redsm[8 * DIM];

    const int g = blockIdx.x, t = threadIdx.x;
    const int wid = t >> 6, lane = t & 63;

    sc[t] = sc1g[g * NPG1 + t];
    __syncthreads();

    {
        float my = sc[t];
        int r = 0;
        const float4* sc4 = (const float4*)sc;
        #pragma unroll 4
        for (int j4 = 0; j4 < NPG1 / 4; ++j4) {
            float4 v = sc4[j4];
            int j = 4 * j4;
            r += (v.x > my) | ((v.x == my) & (j     < t));
            r += (v.y > my) | ((v.y == my) & (j + 1 < t));
            r += (v.z > my) | ((v.z == my) & (j + 2 < t));
            r += (v.w > my) | ((v.w == my) & (j + 3 < t));
        }
        rnk[t] = r;
        invr[g * NPG1 + t] = (r < K1) ? r : -1;
    }
    __syncthreads();

    float wlv[LB], wrv[LB];
    #pragma unroll
    for (int j = 0; j < LB; ++j) { wlv[j] = Wl[j * DIM + lane]; wrv[j] = Wr[j * DIM + lane]; }
    const float blv = bl[lane];

    float mx = -INFINITY, sm = 0.f;
    for (int n = wid; n < NPG1; n += 8) {
        int r = rnk[n];
        if (r >= K1) continue;
        const float* mp = meanv + (size_t)(g * NPG1 + n) * LB;
        const float* xp = x + (size_t)(g * NPG1 + n) * LB;
        float al = 0.f, ar = 0.f;
        #pragma unroll
        for (int j = 0; j < LB; ++j) {
            al += mp[j] * wlv[j];
            ar += xp[j] * wrv[j];
        }
        float acc = fmaxf(blv + al + ar, 0.f);
        float v = acc * sc[n];
        h1p[((size_t)g * K1 + r) * DIM + lane] = v;
        mx = fmaxf(mx, v);
        sm += v;
    }
    redmx[wid * DIM + lane] = mx;
    redsm[wid * DIM + lane] = sm;
    __syncthreads();
    if (wid == 0) {
        float m2 = redmx[lane], s2 = redsm[lane];
        #pragma unroll
        for (int w = 1; w < 8; ++w) {
            m2 = fmaxf(m2, redmx[w * DIM + lane]);
            s2 += redsm[w * DIM + lane];
        }
        x1buf[g * 2 * DIM + lane]       = m2;
        x1buf[g * 2 * DIM + DIM + lane] = s2 * (1.0f / (float)K1);
    }
}

// ---------------------------------------------------------------------------
// csr_init: fill csr with ZROW, zero indeg, zero Y_l's zero-row.
// grid = N1*CSRW/1024 = 4920 exact.
__global__ __launch_bounds__(256)
void csr_init_kernel(int* __restrict__ csr,
                     int* __restrict__ indeg,
                     float* __restrict__ Yl) {
    const int i = blockIdx.x * 256 + threadIdx.x;
    int4 v; v.x = ZROW; v.y = ZROW; v.z = ZROW; v.w = ZROW;
    ((int4*)csr)[i] = v;
    if (i < N1) indeg[i] = 0;
    if (i < DIM) Yl[ZROW * DIM + i] = 0.f;
}

// ---------------------------------------------------------------------------
// csr_fill: edge-parallel.
__global__ __launch_bounds__(256)
void csr_fill_kernel(const int* __restrict__ eidx,
                     const int* __restrict__ invr,
                     int* __restrict__ csr,
                     int* __restrict__ indeg) {
    int e = blockIdx.x * 256 + threadIdx.x;       // grid = EDG/256 exact
    int s = eidx[e];
    int d = eidx[EDG + e];
    int rs = invr[s];
    int rd = invr[d];
    if ((rs | rd) < 0) return;
    int g = s >> 9;
    int gn = g * K1 + rd;
    int slot = atomicAdd(&indeg[gn], 1);
    csr[gn * CSRW + slot] = g * K1 + rs;
}

// ---------------------------------------------------------------------------
// gemm12: Y_l = h1p@Wl (IN-PLACE over h1p), Y_r = h1p@Wr + bl -> Yr region.
// 8 waves x 8 nodes per block; weights in LDS (32KB); lane = output col.
__global__ __launch_bounds__(512)
void gemm12_kernel(float* __restrict__ hY,       // h1p in, Y_l out (in-place)
                   float* __restrict__ Yr,       // Y_r out (h2 region)
                   const float* __restrict__ Wl,
                   const float* __restrict__ bl,
                   const float* __restrict__ Wr) {
    __shared__ __align__(16) float wls[DIM * DIM];
    __shared__ __align__(16) float wrs[DIM * DIM];
    const int t = threadIdx.x, wid = t >> 6, lane = t & 63;
    for (int i = t; i < DIM * DIM; i += 512) { wls[i] = Wl[i]; wrs[i] = Wr[i]; }
    __syncthreads();

    const int cid = ((int)blockIdx.x & 7) * (GRIDG / 8) + ((int)blockIdx.x >> 3);
    const int nb = cid * 64 + wid * 8;
    const float blv = bl[lane];

    float la[8] = {0.f,0.f,0.f,0.f,0.f,0.f,0.f,0.f};
    float ra[8] = {0.f,0.f,0.f,0.f,0.f,0.f,0.f,0.f};
    #pragma unroll 4
    for (int j4 = 0; j4 < DIM / 4; ++j4) {
        const int jb = 4 * j4 * DIM + lane;
        float w0 = wls[jb],           w1 = wls[jb + DIM];
        float w2 = wls[jb + 2 * DIM], w3 = wls[jb + 3 * DIM];
        float u0 = wrs[jb],           u1 = wrs[jb + DIM];
        float u2 = wrs[jb + 2 * DIM], u3 = wrs[jb + 3 * DIM];
        #pragma unroll
        for (int i = 0; i < 8; ++i) {
            float4 a = *(const float4*)&hY[(nb + i) * DIM + 4 * j4];
            la[i] += a.x * w0 + a.y * w1 + a.z * w2 + a.w * w3;
            ra[i] += a.x * u0 + a.y * u1 + a.z * u2 + a.w * u3;
        }
    }
    #pragma unroll
    for (int i = 0; i < 8; ++i) {
        hY[(nb + i) * DIM + lane] = la[i];       // all reads of these rows done
        Yr[(nb + i) * DIM + lane] = ra[i] + blv;
    }
}

// ---------------------------------------------------------------------------
// gather2: h2 = relu(invd * sum(Y_l[nbr]) + Y_r) in-place over Yr, + score2.
// 4 waves x 4 nodes per block; no LDS; unconditional padded-CSR gather.
__global__ __launch_bounds__(256)
void gather2_kernel(const float* __restrict__ Yl,
                    float* __restrict__ Yh,      // Y_r in, h2 out (in-place)
                    const int* __restrict__ csr,
                    const int* __restrict__ indeg,
                    const float* __restrict__ pw,
                    float* __restrict__ sc2g) {
    const int t = threadIdx.x, wid = t >> 6, lane = t & 63;
    const int cid = ((int)blockIdx.x & 7) * (GRIDA / 8) + ((int)blockIdx.x >> 3);
    const int n0 = cid * 16 + wid * 4;

    const float pwv = pw[lane];
    float q = pwv * pwv;
    #pragma unroll
    for (int o = 32; o; o >>= 1) q += __shfl_xor(q, o);
    const float inv_nrm = 1.f / sqrtf(q);

    #pragma unroll
    for (int i = 0; i < 4; ++i) {
        const int n = n0 + i;
        const int dg = indeg[n];
        const int4* cr = (const int4*)&csr[n * CSRW];
        float acc = 0.f;
        #pragma unroll 2
        for (int kc = 0; 4 * kc < dg; ++kc) {
            int4 id = cr[kc];
            acc += Yl[id.x * DIM + lane];
            acc += Yl[id.y * DIM + lane];
            acc += Yl[id.z * DIM + lane];
            acc += Yl[id.w * DIM + lane];
        }
        const float invd = 1.f / fmaxf((float)dg, 1.f);
        const float h = fmaxf(acc * invd + Yh[n * DIM + lane], 0.f);
        Yh[n * DIM + lane] = h;
        float p = h * pwv;
        #pragma unroll
        for (int o = 32; o; o >>= 1) p += __shfl_xor(p, o);
        if (lane == 0) sc2g[n] = tanhf(p * inv_nrm);
    }
}

// ---------------------------------------------------------------------------
// Pool2 + readout2 + final MLP (one block per graph).
__global__ __launch_bounds__(512)
void pool2_mlp_kernel(const float* __restrict__ sc2g,
                      const float* __restrict__ h2,
                      const float* __restrict__ x1buf,
                      const float* __restrict__ W1,
                      const float* __restrict__ b1,
                      const float* __restrict__ W2,
                      const float* __restrict__ b2,
                      float* __restrict__ out) {
    __shared__ __align__(16) float sc2[412];
    __shared__ int   rnk2[K1];
    __shared__ float redmx[8 * DIM];
    __shared__ float redsm[8 * DIM];
    __shared__ float zy[2 * DIM + DIM];

    const int g = blockIdx.x, t = threadIdx.x;
    const int wid = t >> 6, lane = t & 63;

    if (t < K1) sc2[t] = sc2g[g * K1 + t];
    if (t >= K1 && t < 412) sc2[t] = -INFINITY;
    __syncthreads();

    if (t < K1) {
        float my = sc2[t];
        int r = 0;
        const float4* sc4 = (const float4*)sc2;
        #pragma unroll 4
        for (int j4 = 0; j4 < 103; ++j4) {
            float4 v = sc4[j4];
            int j = 4 * j4;
            r += (v.x > my) | ((v.x == my) & (j     < t));
            r += (v.y > my) | ((v.y == my) & (j + 1 < t));
            r += (v.z > my) | ((v.z == my) & (j + 2 < t));
            r += (v.w > my) | ((v.w == my) & (j + 3 < t));
        }
        rnk2[t] = r;
    }
    __syncthreads();

    float mx = -INFINITY, sm = 0.f;
    for (int n = wid; n < K1; n += 8) {
        if (rnk2[n] < K2) {
            float v = h2[((size_t)g * K1 + n) * DIM + lane] * sc2[n];
            mx = fmaxf(mx, v);
            sm += v;
        }
    }
    redmx[wid * DIM + lane] = mx;
    redsm[wid * DIM + lane] = sm;
    __syncthreads();
    if (wid == 0) {
        float m2 = redmx[lane], s2 = redsm[lane];
        #pragma unroll
        for (int w = 1; w < 8; ++w) {
            m2 = fmaxf(m2, redmx[w * DIM + lane]);
            s2 += redsm[w * DIM + lane];
        }
        zy[lane]       = x1buf[g * 2 * DIM + lane]       + m2;
        zy[DIM + lane] = x1buf[g * 2 * DIM + DIM + lane] + s2 * (1.0f / (float)K2);
    }
    __syncthreads();

    if (t < DIM) {
        float a = b1[t];
        #pragma unroll 8
        for (int j = 0; j < 2 * DIM; ++j) a += zy[j] * W1[j * DIM + t];
        zy[2 * DIM + t] = fmaxf(a, 0.f);
    }
    __syncthreads();
    if (t < OUTF) {
        float a = b2[t];
        #pragma unroll
        for (int j = 0; j < DIM; ++j) a += zy[2 * DIM + j] * W2[j * OUTF + t];
        out[g * OUTF + t] = a;
    }
}

// ---------------------------------------------------------------------------
extern "C" void kernel_launch(void* const* d_in, const int* in_sizes, int n_in,
                              void* d_out, int out_size, void* d_ws, size_t ws_size,
                              hipStream_t stream) {
    (void)in_sizes; (void)n_in; (void)out_size; (void)ws_size;
    const float* x       = (const float*)d_in[0];
    const int*   eidx    = (const int*)d_in[1];
    const float* c1_Wl   = (const float*)d_in[2];
    const float* c1_bl   = (const float*)d_in[3];
    const float* c1_Wr   = (const float*)d_in[4];
    const float* pool1_w = (const float*)d_in[5];
    const float* c2_Wl   = (const float*)d_in[6];
    const float* c2_bl   = (const float*)d_in[7];
    const float* c2_Wr   = (const float*)d_in[8];
    const float* pool2_w = (const float*)d_in[9];
    const float* lin1_W  = (const float*)d_in[10];
    const float* lin1_b  = (const float*)d_in[11];
    const float* lin2_W  = (const float*)d_in[12];
    const float* lin2_b  = (const float*)d_in[13];
    float* out = (float*)d_out;

    // Workspace layout (256-aligned), ~76 MB with overlays
    char* w = (char*)d_ws;
    size_t off = 0;
    auto alloc = [&](size_t bytes) {
        void* p = w + off;
        off = (off + bytes + 255) & ~(size_t)255;
        return p;
    };
    float* h1p   = (float*)alloc((size_t)(N1 + 1) * DIM * 4);  // 26.9 MB; becomes Y_l
    int*   invr  = (int*)  alloc((size_t)NN * 4);              // 512 KB
    float* x1buf = (float*)alloc((size_t)BGR * 2 * DIM * 4);   // 128 KB
    float* sc2g  = (float*)alloc((size_t)N1 * 4);              // 410 KB
    int*   indeg = (int*)  alloc((size_t)N1 * 4);              // 410 KB
    char*  h2reg = (char*) alloc((size_t)N1 * DIM * 4);        // 26.9 MB; Y_r then h2
    char*  csreg = (char*) alloc((size_t)N1 * CSRW * 4);       // 20.2 MB

    // Overlays: s1 partials in h2 region (dead before gemm12 writes Y_r);
    // mean+sc1 in csr region (dead before csr_init writes csr).
    float* Yl     = h1p;                                       // in-place
    float* Yh     = (float*)h2reg;                             // Y_r -> h2
    float* part_s = (float*)h2reg;                             // 10.5 MB
    int*   part_d = (int*)(part_s + (size_t)BGR * SPLIT * NPG1 * LB); // 2.1 MB
    int*   csr    = (int*)csreg;
    float* meanv  = (float*)csreg;                             // 2.6 MB
    float* sc1g   = meanv + (size_t)NN * LB;                   // 512 KB

    s1_agg_kernel<<<BGR * SPLIT, 512, 0, stream>>>(x, eidx, part_s, part_d);
    s1_score_kernel<<<NN / 256, 256, 0, stream>>>(x, part_s, part_d, c1_Wl,
                                                  c1_bl, c1_Wr, pool1_w,
                                                  meanv, sc1g);
    s1_rankpool_kernel<<<BGR, 512, 0, stream>>>(x, meanv, sc1g, c1_Wl, c1_bl,
                                                c1_Wr, h1p, invr, x1buf);
    csr_init_kernel<<<N1 * CSRW / 1024, 256, 0, stream>>>(csr, indeg, Yl);
    csr_fill_kernel<<<EDG / 256, 256, 0, stream>>>(eidx, invr, csr, indeg);
    gemm12_kernel<<<GRIDG, 512, 0, stream>>>(Yl, Yh, c2_Wl, c2_bl, c2_Wr);
    gather2_kernel<<<GRIDA, 256, 0, stream>>>(Yl, Yh, csr, indeg, pool2_w, sc2g);
    pool2_mlp_kernel<<<BGR, 512, 0, stream>>>(sc2g, Yh, x1buf, lin1_W, lin1_b,
                                              lin2_W, lin2_b, out);
}